// Round 9
// baseline (345.571 us; speedup 1.0000x reference)
//
#include <hip/hip_runtime.h>

#define NSRC   100000
#define NDST0  30000
#define NDST1  8000
#define E0N    200000
#define E1N    80000
#define HD     256   // H*D
#define DD     64
#define CAP    64    // max edges per dst bucket

typedef short bf16x8 __attribute__((ext_vector_type(8)));
typedef float f32x4  __attribute__((ext_vector_type(4)));

static __device__ __forceinline__ unsigned short f2bf(float f) {
    unsigned u = __float_as_uint(f);
    u += 0x7fffu + ((u >> 16) & 1u);           // RNE
    return (unsigned short)(u >> 16);
}
static __device__ __forceinline__ unsigned pack2(float a, float b) {
    return (unsigned)f2bf(a) | ((unsigned)f2bf(b) << 16);
}
static __device__ __forceinline__ void fma4(float4& a, float s, const float4& b) {
    a.x = fmaf(s, b.x, a.x); a.y = fmaf(s, b.y, a.y);
    a.z = fmaf(s, b.z, a.z); a.w = fmaf(s, b.w, a.w);
}
static __device__ __forceinline__ float dot4(const float4& a, const float4& b) {
    return fmaf(a.x, b.x, fmaf(a.y, b.y, fmaf(a.z, b.z, a.w * b.w)));
}
static __device__ __forceinline__ float4 ld_bf4(const unsigned short* p) {
    uint2 u = *reinterpret_cast<const uint2*>(p);
    float4 r;
    r.x = __uint_as_float(u.x << 16);
    r.y = __uint_as_float(u.x & 0xffff0000u);
    r.z = __uint_as_float(u.y << 16);
    r.w = __uint_as_float(u.y & 0xffff0000u);
    return r;
}
static __device__ __forceinline__ void red4(float4& a, int m) {
    a.x += __shfl_xor(a.x, m, 64);
    a.y += __shfl_xor(a.y, m, 64);
    a.z += __shfl_xor(a.z, m, 64);
    a.w += __shfl_xor(a.w, m, 64);
}

// Fused: wl/wr projection prep (blocks 0..WLRB-1) + W^T bf16 transpose (blocks WLRB..WLRB+2).
template<int K>
__global__ void k_wprep(const float* __restrict__ W, const float* __restrict__ al,
                        const float* __restrict__ ar, float* __restrict__ wl,
                        float* __restrict__ wr, unsigned short* __restrict__ Wt)
{
    constexpr int WLRB = (3 * K * 4) / 256;   // 3 (K=64) or 6 (K=128)
    int bx = blockIdx.x;
    if (bx < WLRB) {
        int tid = bx * 256 + threadIdx.x;
        int r = tid / (K * 4);
        int rem = tid - r * K * 4;
        int k = rem >> 2, h = rem & 3;
        const float* wrow = W + (size_t)r * K * HD + (size_t)k * HD + h * DD;
        const float* a_l = al + r * HD + h * DD;
        const float* a_r = ar + r * HD + h * DD;
        float sl = 0.f, sr = 0.f;
        for (int d = 0; d < DD; ++d) {
            float w = wrow[d];
            sl = fmaf(w, a_l[d], sl);
            sr = fmaf(w, a_r[d], sr);
        }
        wl[r * 512 + k * 4 + h] = sl;
        wr[r * 512 + k * 4 + h] = sr;
    } else {
        int r = bx - WLRB;
        const float* Wr = W + (size_t)r * K * HD;
        unsigned short* Wtr = Wt + (size_t)r * 256 * K;
        int c = threadIdx.x;
        #pragma unroll 4
        for (int k = 0; k < K; k += 2) {
            float a = Wr[(size_t)k * HD + c];
            float b = Wr[(size_t)(k + 1) * HD + c];
            *reinterpret_cast<unsigned*>(Wtr + (size_t)c * K + k) = pack2(a, b);
        }
    }
}

// Fused el/er prep for BOTH node sets in one launch (block half-split), plus
// bf16 mirror write of X (gather source for k_agg3). Spill-free static indexing.
// item half: el_ii,el_iu + er_ii,er_ui ; user half: el_ui + er_iu.
template<int K, bool MIRROR>
__global__ __launch_bounds__(256) void k_prep_x2(const float* __restrict__ XA,
                                                 const float* __restrict__ XB,
                                                 int M, int nd, int bpr,
                                                 const float* __restrict__ wl3,
                                                 const float* __restrict__ wr3,
                                                 float* __restrict__ el3,
                                                 float* __restrict__ er3,
                                                 unsigned short* __restrict__ XbA,
                                                 unsigned short* __restrict__ XbB)
{
    int bx = blockIdx.x;
    const bool item = bx < bpr;
    int row = (item ? bx : bx - bpr) * 256 + threadIdx.x;
    if (row >= M) return;
    const float* X = item ? XA : XB;
    const float4* xv = reinterpret_cast<const float4*>(X + (size_t)row * K);

    if (MIRROR) {
        unsigned short* xbrow = (item ? XbA : XbB) + (size_t)row * K;
        #pragma unroll
        for (int c2 = 0; c2 < K / 8; ++c2) {
            float4 a = xv[2 * c2], b = xv[2 * c2 + 1];
            uint4 w;
            w.x = pack2(a.x, a.y); w.y = pack2(a.z, a.w);
            w.z = pack2(b.x, b.y); w.w = pack2(b.z, b.w);
            reinterpret_cast<uint4*>(xbrow)[c2] = w;
        }
    }

    const float4* wlAv = reinterpret_cast<const float4*>(item ? wl3 : wl3 + 1024);
    const float4* wlBv = reinterpret_cast<const float4*>(wl3 + 512);
    float4 aA = make_float4(0.f, 0.f, 0.f, 0.f), aB = aA;
    #pragma unroll
    for (int c = 0; c < K / 4; ++c) {
        float4 x4 = xv[c];
        fma4(aA, x4.x, wlAv[c * 4 + 0]); fma4(aA, x4.y, wlAv[c * 4 + 1]);
        fma4(aA, x4.z, wlAv[c * 4 + 2]); fma4(aA, x4.w, wlAv[c * 4 + 3]);
        if (item) {
            fma4(aB, x4.x, wlBv[c * 4 + 0]); fma4(aB, x4.y, wlBv[c * 4 + 1]);
            fma4(aB, x4.z, wlBv[c * 4 + 2]); fma4(aB, x4.w, wlBv[c * 4 + 3]);
        }
    }
    if (item) {
        *reinterpret_cast<float4*>(el3 + (size_t)row * 4) = aA;                       // el_ii
        *reinterpret_cast<float4*>(el3 + (size_t)NSRC * 4 + (size_t)row * 4) = aB;    // el_iu
    } else {
        *reinterpret_cast<float4*>(el3 + (size_t)2 * NSRC * 4 + (size_t)row * 4) = aA; // el_ui
    }
    if (row < nd) {
        const float4* wrAv = reinterpret_cast<const float4*>(item ? wr3 : wr3 + 512);
        const float4* wrBv = reinterpret_cast<const float4*>(wr3 + 1024);
        float4 rA = make_float4(0.f, 0.f, 0.f, 0.f), rB = rA;
        #pragma unroll
        for (int c = 0; c < K / 4; ++c) {
            float4 x4 = xv[c];
            fma4(rA, x4.x, wrAv[c * 4 + 0]); fma4(rA, x4.y, wrAv[c * 4 + 1]);
            fma4(rA, x4.z, wrAv[c * 4 + 2]); fma4(rA, x4.w, wrAv[c * 4 + 3]);
            if (item) {
                fma4(rB, x4.x, wrBv[c * 4 + 0]); fma4(rB, x4.y, wrBv[c * 4 + 1]);
                fma4(rB, x4.z, wrBv[c * 4 + 2]); fma4(rB, x4.w, wrBv[c * 4 + 3]);
            }
        }
        if (item) {
            *reinterpret_cast<float4*>(er3 + (size_t)row * 4) = rA;                        // er_ii
            *reinterpret_cast<float4*>(er3 + (size_t)2 * NDST0 * 4 + (size_t)row * 4) = rB; // er_ui
        } else {
            *reinterpret_cast<float4*>(er3 + (size_t)NDST0 * 4 + (size_t)row * 4) = rA;    // er_iu
        }
    }
}

// Bucket edges by dst for 3 relations in one launch; store SRC NODE directly.
__global__ void k_fill3(const int* __restrict__ ed0, const int* __restrict__ ed1,
                        const int* __restrict__ ed2, const int* __restrict__ es0,
                        const int* __restrict__ es1, const int* __restrict__ es2,
                        int* __restrict__ cnt, int* __restrict__ bsrc,
                        int E, int nd, int bpr)
{
    int bx = blockIdx.x;
    int r = (bx >= 2 * bpr) ? 2 : (bx >= bpr ? 1 : 0);
    int e = (bx - r * bpr) * 256 + threadIdx.x;
    if (e >= E) return;
    const int* ed = (r == 0) ? ed0 : (r == 1 ? ed1 : ed2);
    const int* es = (r == 0) ? es0 : (r == 1 ? es1 : es2);
    int d = ed[e];
    int c = atomicAdd(&cnt[(size_t)r * nd + d], 1);
    if (c < CAP) bsrc[((size_t)r * nd + d) * CAP + c] = es[e];
}

// x-space aggregation, 3 relations per launch, MLP-widened, wave-uniform shfl
// loop, bf16 gather source. aggX[r][dst][h][0:K] (bf16, f32 accum).
template<int K>
__global__ __launch_bounds__(256) void k_agg3(const int* __restrict__ cnt,
                                              const int* __restrict__ bsrc,
                                              const float* __restrict__ el3,
                                              const float* __restrict__ er3,
                                              const unsigned short* __restrict__ xsA,
                                              const unsigned short* __restrict__ xsB,
                                              unsigned short* __restrict__ aggX,
                                              int nd, int bpr)
{
    constexpr int NV = K / 64;                 // float4 chunks per lane
    int bx = blockIdx.x;
    int r = (bx >= 2 * bpr) ? 2 : (bx >= bpr ? 1 : 0);
    int wid = ((bx - r * bpr) * 256 + (int)threadIdx.x) >> 6;
    int lane = threadIdx.x & 63;
    if (wid >= nd) return;
    int q = lane & 15, g = lane >> 4;
    const float* el = el3 + (size_t)r * NSRC * 4;
    const unsigned short* xsrc = (r < 2) ? xsA : xsB;
    int c = cnt[(size_t)r * nd + wid]; if (c > CAP) c = CAP;   // wave-uniform
    const int* lst = bsrc + ((size_t)r * nd + wid) * CAP;
    float4 er4 = *reinterpret_cast<const float4*>(er3 + (size_t)r * NDST0 * 4 + (size_t)wid * 4);

    int s_own = 0;
    float4 ex_own = make_float4(0.f, 0.f, 0.f, 0.f);
    if (lane < c) {
        s_own = lst[lane];
        float4 e4 = *reinterpret_cast<const float4*>(el + (size_t)s_own * 4);
        e4.x += er4.x; e4.y += er4.y; e4.z += er4.z; e4.w += er4.w;
        e4.x = e4.x > 0.f ? e4.x : 0.2f * e4.x;
        e4.y = e4.y > 0.f ? e4.y : 0.2f * e4.y;
        e4.z = e4.z > 0.f ? e4.z : 0.2f * e4.z;
        e4.w = e4.w > 0.f ? e4.w : 0.2f * e4.w;
        ex_own.x = __expf(e4.x); ex_own.y = __expf(e4.y);
        ex_own.z = __expf(e4.z); ex_own.w = __expf(e4.w);   // shift-invariant softmax
    }

    float4 acc[4][NV];
    #pragma unroll
    for (int h = 0; h < 4; ++h)
        #pragma unroll
        for (int v = 0; v < NV; ++v) acc[h][v] = make_float4(0.f, 0.f, 0.f, 0.f);
    float4 den = make_float4(0.f, 0.f, 0.f, 0.f);

    const int nt = (c + 3) >> 2;               // wave-uniform trip count
    for (int t = 0; t < nt; ++t) {
        int i = g + 4 * t;
        int ilane = i & 63;
        int   s   = __shfl(s_own,    ilane, 64);   // full-exec shfl
        float ex0 = __shfl(ex_own.x, ilane, 64);
        float ex1 = __shfl(ex_own.y, ilane, 64);
        float ex2 = __shfl(ex_own.z, ilane, 64);
        float ex3 = __shfl(ex_own.w, ilane, 64);
        if (i < c) {
            const unsigned short* xp = xsrc + (size_t)s * K + q * 4 * NV;
            #pragma unroll
            for (int v = 0; v < NV; ++v) {
                float4 x4 = ld_bf4(xp + v * 4);
                fma4(acc[0][v], ex0, x4);
                fma4(acc[1][v], ex1, x4);
                fma4(acc[2][v], ex2, x4);
                fma4(acc[3][v], ex3, x4);
            }
            den.x += ex0; den.y += ex1; den.z += ex2; den.w += ex3;
        }
    }
    #pragma unroll
    for (int m = 16; m < 64; m <<= 1) {
        #pragma unroll
        for (int h = 0; h < 4; ++h)
            #pragma unroll
            for (int v = 0; v < NV; ++v) red4(acc[h][v], m);
        red4(den, m);
    }
    float invh[4];
    invh[0] = den.x > 0.f ? 1.f / den.x : 0.f;
    invh[1] = den.y > 0.f ? 1.f / den.y : 0.f;
    invh[2] = den.z > 0.f ? 1.f / den.z : 0.f;
    invh[3] = den.w > 0.f ? 1.f / den.w : 0.f;
    #pragma unroll
    for (int h = 0; h < 4; ++h) {
        unsigned short* op = aggX + ((size_t)r * nd * 4 + (size_t)wid * 4 + h) * K + q * 4 * NV;
        if (NV == 1) {
            uint2 w;
            w.x = pack2(acc[h][0].x * invh[h], acc[h][0].y * invh[h]);
            w.y = pack2(acc[h][0].z * invh[h], acc[h][0].w * invh[h]);
            *reinterpret_cast<uint2*>(op) = w;
        } else {
            uint4 w;
            w.x = pack2(acc[h][0].x * invh[h], acc[h][0].y * invh[h]);
            w.y = pack2(acc[h][0].z * invh[h], acc[h][0].w * invh[h]);
            w.z = pack2(acc[h][1].x * invh[h], acc[h][1].y * invh[h]);
            w.w = pack2(acc[h][1].z * invh[h], acc[h][1].w * invh[h]);
            *reinterpret_cast<uint4*>(op) = w;
        }
    }
}

// GEMM for 3 relations in one launch. out (bf16) stride NDST0*HD per rel.
template<int K>
__global__ __launch_bounds__(256) void k_gemm3(const unsigned short* __restrict__ aggX,
                                               const unsigned short* __restrict__ Wt3,
                                               unsigned short* __restrict__ outb,
                                               int nd, int bpr)
{
    int bx = blockIdx.x;
    int r = (bx >= 2 * bpr) ? 2 : (bx >= bpr ? 1 : 0);
    const unsigned short* A  = aggX + (size_t)r * nd * 4 * K;
    const unsigned short* Wt = Wt3 + (size_t)r * 256 * K;
    unsigned short* ob = outb + (size_t)r * NDST0 * HD;
    const int lane = threadIdx.x & 63;
    const int wv = threadIdx.x >> 6;          // = head
    const int r0 = (bx - r * bpr) * 16;
    const int rr = lane & 15, kg = lane >> 4;
    f32x4 acc[4] = {{0.f,0.f,0.f,0.f},{0.f,0.f,0.f,0.f},{0.f,0.f,0.f,0.f},{0.f,0.f,0.f,0.f}};
    const unsigned short* ap = A + ((size_t)(r0 + rr) * 4 + wv) * K + kg * 8;
    #pragma unroll
    for (int kb = 0; kb < K; kb += 32) {
        bf16x8 a = *reinterpret_cast<const bf16x8*>(ap + kb);
        #pragma unroll
        for (int n = 0; n < 4; ++n) {
            const unsigned short* wp = Wt + (size_t)(wv * 64 + n * 16 + rr) * K + kb + kg * 8;
            bf16x8 b = *reinterpret_cast<const bf16x8*>(wp);
            acc[n] = __builtin_amdgcn_mfma_f32_16x16x32_bf16(a, b, acc[n], 0, 0, 0);
        }
    }
    #pragma unroll
    for (int n = 0; n < 4; ++n)
        #pragma unroll
        for (int i = 0; i < 4; ++i)
            ob[(size_t)(r0 + kg * 4 + i) * HD + wv * 64 + n * 16 + rr] = f2bf(acc[n][i]);
}

// Attention pool: 4 nodes per wave, 16 lanes per node (lane owns 4 dims). bf16 sources.
template<int S>
__global__ __launch_bounds__(256) void k_pool2(const unsigned short* __restrict__ srcA, const float* __restrict__ bA,
                                               const unsigned short* __restrict__ srcB, const float* __restrict__ bB,
                                               const float* __restrict__ base, int baseCols,
                                               float* __restrict__ dst, int pitch, int colOff, int n)
{
    int wid = (blockIdx.x * 256 + threadIdx.x) >> 6;
    int lane = threadIdx.x & 63;
    int node = wid * 4 + (lane >> 4);
    int q = lane & 15;
    if (node >= n) return;

    float4 f[S];
    #pragma unroll
    for (int s = 0; s < S; ++s) {
        const unsigned short* sp = (s < 4) ? (srcA + (size_t)node * HD + s * DD)
                                           : (srcB + (size_t)node * HD + (s - 4) * DD);
        const float* bp = (s < 4) ? (bA + s * DD) : (bB + (s - 4) * DD);
        float4 v = ld_bf4(sp + q * 4);
        float4 b = *reinterpret_cast<const float4*>(bp + q * 4);
        v.x += b.x; v.y += b.y; v.z += b.z; v.w += b.w;
        f[s] = v;
    }
    constexpr int NE = S * (S + 1) / 2;
    float gt[NE];
    {
        int idx = 0;
        #pragma unroll
        for (int s = 0; s < S; ++s)
            #pragma unroll
            for (int t = s; t < S; ++t)
                gt[idx++] = dot4(f[s], f[t]);
    }
    #pragma unroll
    for (int m = 1; m < 16; m <<= 1) {
        #pragma unroll
        for (int i = 0; i < NE; ++i) gt[i] += __shfl_xor(gt[i], m, 16);
    }
    auto Gv = [&](int s, int t) -> float {
        int a = s < t ? s : t, b2 = s < t ? t : s;
        return gt[a * S - a * (a - 1) / 2 + (b2 - a)];
    };
    float g[S];
    #pragma unroll
    for (int t = 0; t < S; ++t) g[t] = 0.f;
    #pragma unroll
    for (int s = 0; s < S; ++s) {
        float sc[S];
        float m = -1e30f;
        #pragma unroll
        for (int t = 0; t < S; ++t) { sc[t] = Gv(s, t) * 0.125f; m = sc[t] > m ? sc[t] : m; }
        float pe[S];
        float sum = 0.f;
        #pragma unroll
        for (int t = 0; t < S; ++t) { pe[t] = __expf(sc[t] - m); sum += pe[t]; }
        float inv = 1.f / sum;
        #pragma unroll
        for (int t = 0; t < S; ++t) g[t] += pe[t] * inv;
    }
    float4 o = make_float4(0.f, 0.f, 0.f, 0.f);
    #pragma unroll
    for (int t = 0; t < S; ++t) fma4(o, g[t], f[t]);
    const float is = 1.f / S;
    o.x *= is; o.y *= is; o.z *= is; o.w *= is;
    *reinterpret_cast<float4*>(dst + (size_t)node * pitch + colOff + q * 4) = o;
    for (int c = q * 4; c < baseCols; c += 64) {
        float4 v = *reinterpret_cast<const float4*>(base + (size_t)node * baseCols + c);
        *reinterpret_cast<float4*>(dst + (size_t)node * pitch + c) = v;
    }
}

extern "C" void kernel_launch(void* const* d_in, const int* in_sizes, int n_in,
                              void* d_out, int out_size, void* d_ws, size_t ws_size,
                              hipStream_t stream)
{
    const float* x_user = (const float*)d_in[0];
    const float* x_item = (const float*)d_in[1];
    // rel order within a layer: 0=ii 1=iu 2=ui
    const int* e_s[6] = { (const int*)d_in[2], (const int*)d_in[4], (const int*)d_in[6],
                          (const int*)d_in[8], (const int*)d_in[10], (const int*)d_in[12] };
    const int* e_d[6] = { (const int*)d_in[3], (const int*)d_in[5], (const int*)d_in[7],
                          (const int*)d_in[9], (const int*)d_in[11], (const int*)d_in[13] };
    const float* W0  = (const float*)d_in[14];
    const float* al0 = (const float*)d_in[15];
    const float* ar0 = (const float*)d_in[16];
    const float* b0  = (const float*)d_in[17];
    const float* W1  = (const float*)d_in[18];
    const float* al1 = (const float*)d_in[19];
    const float* ar1 = (const float*)d_in[20];
    const float* b1  = (const float*)d_in[21];
    float* out = (float*)d_out;
    (void)in_sizes; (void)n_in; (void)out_size; (void)ws_size;

    char* p = (char*)d_ws;
    auto take = [&](size_t bytes) { char* r = p; p += (bytes + 255) & ~(size_t)255; return r; };
    unsigned short* out3 = (unsigned short*)take((size_t)3 * NDST0 * HD * 2);  // 46.1 MB
    float* xu1  = (float*)take((size_t)NDST0 * 128 * 4);                       // 15.4 MB
    float* xi1  = (float*)take((size_t)NDST0 * 128 * 4);                       // 15.4 MB
    unsigned short* xib  = (unsigned short*)take((size_t)NSRC * DD * 2);       // 12.8 MB
    unsigned short* xub  = (unsigned short*)take((size_t)NSRC * DD * 2);       // 12.8 MB
    unsigned short* xi1b = (unsigned short*)take((size_t)NDST0 * 128 * 2);     // 7.7 MB
    unsigned short* xu1b = (unsigned short*)take((size_t)NDST0 * 128 * 2);     // 7.7 MB
    unsigned short* aggX = (unsigned short*)take((size_t)3 * NDST0 * 4 * DD * 2); // 46.1 MB (L2 needs 24.6)
    float* el3  = (float*)take((size_t)3 * NSRC * 4 * 4);                      // 4.8 MB
    float* er3  = (float*)take((size_t)3 * NDST0 * 4 * 4);                     // 1.44 MB
    int*   cntA = (int*)take((size_t)3 * NDST0 * 4);
    int*   cntB = (int*)take((size_t)3 * NDST1 * 4);
    int*   bsrcA = (int*)take((size_t)3 * NDST0 * CAP * 4);                    // 23.0 MB
    int*   bsrcB = (int*)take((size_t)3 * NDST1 * CAP * 4);                    // 6.1 MB
    unsigned short* Wt3 = (unsigned short*)take((size_t)3 * 256 * 128 * 2);
    float* wl3  = (float*)take((size_t)3 * 512 * 4);
    float* wr3  = (float*)take((size_t)3 * 512 * 4);
    // total ~200 MB

    unsigned short* out_ii = out3;
    unsigned short* out_iu = out3 + (size_t)NDST0 * HD;
    unsigned short* out_ui = out3 + (size_t)2 * NDST0 * HD;

    // ---- bucket fills for BOTH layers, off the critical path ----
    hipMemsetAsync(cntA, 0, (size_t)3 * NDST0 * 4, stream);
    hipMemsetAsync(cntB, 0, (size_t)3 * NDST1 * 4, stream);
    {
        const int bpr0 = (E0N + 255) / 256;
        k_fill3<<<3 * bpr0, 256, 0, stream>>>(e_d[0], e_d[1], e_d[2], e_s[0], e_s[1], e_s[2],
                                              cntA, bsrcA, E0N, NDST0, bpr0);
        const int bpr1 = (E1N + 255) / 256;
        k_fill3<<<3 * bpr1, 256, 0, stream>>>(e_d[3], e_d[4], e_d[5], e_s[3], e_s[4], e_s[5],
                                              cntB, bsrcB, E1N, NDST1, bpr1);
    }

    // ================= layer 1 (K=64) =================
    k_wprep<64><<<6, 256, 0, stream>>>(W0, al0, ar0, wl3, wr3, Wt3);
    {
        const int bpr = (NSRC + 255) / 256;
        k_prep_x2<64, true><<<2 * bpr, 256, 0, stream>>>(x_item, x_user, NSRC, NDST0, bpr,
                                                         wl3, wr3, el3, er3, xib, xub);
    }
    {
        const int bprA = (NDST0 + 3) / 4;
        k_agg3<64><<<3 * bprA, 256, 0, stream>>>(cntA, bsrcA, el3, er3, xib, xub,
                                                 aggX, NDST0, bprA);
        const int bprG = NDST0 / 16;
        k_gemm3<64><<<3 * bprG, 256, 0, stream>>>(aggX, Wt3, out3, NDST0, bprG);
    }
    k_pool2<4><<<NDST0 / 16, 256, 0, stream>>>(out_iu, b0 + 256, out_iu, b0 + 256,
                                               x_user, 64, xu1, 128, 64, NDST0);
    k_pool2<8><<<NDST0 / 16, 256, 0, stream>>>(out_ii, b0, out_ui, b0 + 512,
                                               x_item, 64, xi1, 128, 64, NDST0);

    // ================= layer 2 (K=128) =================
    k_wprep<128><<<9, 256, 0, stream>>>(W1, al1, ar1, wl3, wr3, Wt3);
    {
        const int bpr = (NDST0 + 255) / 256;
        k_prep_x2<128, true><<<2 * bpr, 256, 0, stream>>>(xi1, xu1, NDST0, NDST1, bpr,
                                                          wl3, wr3, el3, er3, xi1b, xu1b);
    }
    {
        const int bprA = (NDST1 + 3) / 4;
        k_agg3<128><<<3 * bprA, 256, 0, stream>>>(cntB, bsrcB, el3, er3, xi1b, xu1b,
                                                  aggX, NDST1, bprA);
        const int bprG = NDST1 / 16;
        k_gemm3<128><<<3 * bprG, 256, 0, stream>>>(aggX, Wt3, out3, NDST1, bprG);
    }
    k_pool2<4><<<NDST1 / 16, 256, 0, stream>>>(out_iu, b1 + 256, out_iu, b1 + 256,
                                               xu1, 128, out, 192, 128, NDST1);
    k_pool2<8><<<NDST1 / 16, 256, 0, stream>>>(out_ii, b1, out_ui, b1 + 512,
                                               xi1, 128, out + (size_t)NDST1 * 192, 192, 128, NDST1);
}

// Round 10
// 317.497 us; speedup vs baseline: 1.0884x; 1.0884x over previous
//
#include <hip/hip_runtime.h>

#define NSRC   100000
#define NDST0  30000
#define NDST1  8000
#define E0N    200000
#define E1N    80000
#define HD     256   // H*D
#define DD     64
#define CAP    64    // max edges per dst bucket

typedef short bf16x8 __attribute__((ext_vector_type(8)));
typedef float f32x4  __attribute__((ext_vector_type(4)));

static __device__ __forceinline__ unsigned short f2bf(float f) {
    unsigned u = __float_as_uint(f);
    u += 0x7fffu + ((u >> 16) & 1u);           // RNE
    return (unsigned short)(u >> 16);
}
static __device__ __forceinline__ unsigned pack2(float a, float b) {
    return (unsigned)f2bf(a) | ((unsigned)f2bf(b) << 16);
}
static __device__ __forceinline__ void fma4(float4& a, float s, const float4& b) {
    a.x = fmaf(s, b.x, a.x); a.y = fmaf(s, b.y, a.y);
    a.z = fmaf(s, b.z, a.z); a.w = fmaf(s, b.w, a.w);
}
static __device__ __forceinline__ float dot4(const float4& a, const float4& b) {
    return fmaf(a.x, b.x, fmaf(a.y, b.y, fmaf(a.z, b.z, a.w * b.w)));
}
static __device__ __forceinline__ float4 ld_bf4(const unsigned short* p) {
    uint2 u = *reinterpret_cast<const uint2*>(p);
    float4 r;
    r.x = __uint_as_float(u.x << 16);
    r.y = __uint_as_float(u.x & 0xffff0000u);
    r.z = __uint_as_float(u.y << 16);
    r.w = __uint_as_float(u.y & 0xffff0000u);
    return r;
}

// ---- device helpers for the fused setup kernel ----
static __device__ void wlr_prep(const float* __restrict__ W, const float* __restrict__ al,
                                const float* __restrict__ ar, float* __restrict__ wl,
                                float* __restrict__ wr, int K, int tid)
{
    int r = tid / (K * 4);
    int rem = tid - r * K * 4;
    int k = rem >> 2, h = rem & 3;
    const float* wrow = W + (size_t)r * K * HD + (size_t)k * HD + h * DD;
    const float* a_l = al + r * HD + h * DD;
    const float* a_r = ar + r * HD + h * DD;
    float sl = 0.f, sr = 0.f;
    for (int d = 0; d < DD; ++d) {
        float w = wrow[d];
        sl = fmaf(w, a_l[d], sl);
        sr = fmaf(w, a_r[d], sr);
    }
    wl[r * 512 + k * 4 + h] = sl;
    wr[r * 512 + k * 4 + h] = sr;
}
static __device__ void wt_prep(const float* __restrict__ W, unsigned short* __restrict__ Wt,
                               int K, int r, int c)
{
    const float* Wr = W + (size_t)r * K * HD;
    unsigned short* Wtr = Wt + (size_t)r * 256 * K;
    for (int k = 0; k < K; k += 2) {
        float a = Wr[(size_t)k * HD + c];
        float b = Wr[(size_t)(k + 1) * HD + c];
        *reinterpret_cast<unsigned*>(Wtr + (size_t)c * K + k) = pack2(a, b);
    }
}
static __device__ void fill_one(const int* __restrict__ ed, const int* __restrict__ es,
                                int* __restrict__ cnt, int* __restrict__ bsrc,
                                int E, int nd, int r, int e)
{
    if (e >= E) return;
    int d = ed[e];
    int c = atomicAdd(&cnt[(size_t)r * nd + d], 1);
    if (c < CAP) bsrc[((size_t)r * nd + d) * CAP + c] = es[e];
}

// One launch: L1 fills, L2 fills, wl/wr prep both layers, W^T both layers.
__global__ void k_setup(const int* ed0, const int* ed1, const int* ed2,
                        const int* es0, const int* es1, const int* es2,
                        const int* ed3, const int* ed4, const int* ed5,
                        const int* es3, const int* es4, const int* es5,
                        int* cntA, int* bsrcA, int* cntB, int* bsrcB,
                        const float* W0, const float* al0, const float* ar0,
                        const float* W1, const float* al1, const float* ar1,
                        float* wlA, float* wrA, unsigned short* WtA,
                        float* wlB, float* wrB, unsigned short* WtB,
                        int bpr0, int bpr1)
{
    int bx = blockIdx.x;
    int tid = threadIdx.x;
    if (bx < 3 * bpr0) {
        int r = (bx >= 2 * bpr0) ? 2 : (bx >= bpr0 ? 1 : 0);
        int e = (bx - r * bpr0) * 256 + tid;
        const int* ed = (r == 0) ? ed0 : (r == 1 ? ed1 : ed2);
        const int* es = (r == 0) ? es0 : (r == 1 ? es1 : es2);
        fill_one(ed, es, cntA, bsrcA, E0N, NDST0, r, e);
        return;
    }
    bx -= 3 * bpr0;
    if (bx < 3 * bpr1) {
        int r = (bx >= 2 * bpr1) ? 2 : (bx >= bpr1 ? 1 : 0);
        int e = (bx - r * bpr1) * 256 + tid;
        const int* ed = (r == 0) ? ed3 : (r == 1 ? ed4 : ed5);
        const int* es = (r == 0) ? es3 : (r == 1 ? es4 : es5);
        fill_one(ed, es, cntB, bsrcB, E1N, NDST1, r, e);
        return;
    }
    bx -= 3 * bpr1;
    if (bx < 3)       wlr_prep(W0, al0, ar0, wlA, wrA, 64,  bx * 256 + tid);
    else if (bx < 9)  wlr_prep(W1, al1, ar1, wlB, wrB, 128, (bx - 3) * 256 + tid);
    else if (bx < 12) wt_prep(W0, WtA, 64,  bx - 9,  tid);
    else              wt_prep(W1, WtB, 128, bx - 12, tid);
}

// Fused el/er prep for both node sets in one launch (block half-split).
// item half: el_ii,el_iu + er_ii,er_ui ; user half: el_ui + er_iu.
template<int K>
__global__ __launch_bounds__(256) void k_prep_x2(const float* __restrict__ XA,
                                                 const float* __restrict__ XB,
                                                 int M, int nd, int bpr,
                                                 const float* __restrict__ wl3,
                                                 const float* __restrict__ wr3,
                                                 float* __restrict__ el3,
                                                 float* __restrict__ er3)
{
    int bx = blockIdx.x;
    const bool item = bx < bpr;
    int row = (item ? bx : bx - bpr) * 256 + threadIdx.x;
    if (row >= M) return;
    const float* X = item ? XA : XB;
    const float4* xv = reinterpret_cast<const float4*>(X + (size_t)row * K);

    const float4* wlAv = reinterpret_cast<const float4*>(item ? wl3 : wl3 + 1024);
    const float4* wlBv = reinterpret_cast<const float4*>(wl3 + 512);
    float4 aA = make_float4(0.f, 0.f, 0.f, 0.f), aB = aA;
    #pragma unroll
    for (int c = 0; c < K / 4; ++c) {
        float4 x4 = xv[c];
        fma4(aA, x4.x, wlAv[c * 4 + 0]); fma4(aA, x4.y, wlAv[c * 4 + 1]);
        fma4(aA, x4.z, wlAv[c * 4 + 2]); fma4(aA, x4.w, wlAv[c * 4 + 3]);
        if (item) {
            fma4(aB, x4.x, wlBv[c * 4 + 0]); fma4(aB, x4.y, wlBv[c * 4 + 1]);
            fma4(aB, x4.z, wlBv[c * 4 + 2]); fma4(aB, x4.w, wlBv[c * 4 + 3]);
        }
    }
    if (item) {
        *reinterpret_cast<float4*>(el3 + (size_t)row * 4) = aA;                        // el_ii
        *reinterpret_cast<float4*>(el3 + (size_t)NSRC * 4 + (size_t)row * 4) = aB;     // el_iu
    } else {
        *reinterpret_cast<float4*>(el3 + (size_t)2 * NSRC * 4 + (size_t)row * 4) = aA; // el_ui
    }
    if (row < nd) {
        const float4* wrAv = reinterpret_cast<const float4*>(item ? wr3 : wr3 + 512);
        const float4* wrBv = reinterpret_cast<const float4*>(wr3 + 1024);
        float4 rA = make_float4(0.f, 0.f, 0.f, 0.f), rB = rA;
        #pragma unroll
        for (int c = 0; c < K / 4; ++c) {
            float4 x4 = xv[c];
            fma4(rA, x4.x, wrAv[c * 4 + 0]); fma4(rA, x4.y, wrAv[c * 4 + 1]);
            fma4(rA, x4.z, wrAv[c * 4 + 2]); fma4(rA, x4.w, wrAv[c * 4 + 3]);
            if (item) {
                fma4(rB, x4.x, wrBv[c * 4 + 0]); fma4(rB, x4.y, wrBv[c * 4 + 1]);
                fma4(rB, x4.z, wrBv[c * 4 + 2]); fma4(rB, x4.w, wrBv[c * 4 + 3]);
            }
        }
        if (item) {
            *reinterpret_cast<float4*>(er3 + (size_t)row * 4) = rA;                         // er_ii
            *reinterpret_cast<float4*>(er3 + (size_t)2 * NDST0 * 4 + (size_t)row * 4) = rB; // er_ui
        } else {
            *reinterpret_cast<float4*>(er3 + (size_t)NDST0 * 4 + (size_t)row * 4) = rA;     // er_iu
        }
    }
}

// x-space aggregation, head-per-group: group g owns head g, iterates ALL c edges.
// No cross-group reduction. ex broadcast via LDS (per-wave stripe), s via shfl.
// Wave-uniform loop bound; 4 groups read the same x row -> one coalesced fetch.
template<int K>
__global__ __launch_bounds__(256) void k_agg3(const int* __restrict__ cnt,
                                              const int* __restrict__ bsrc,
                                              const float* __restrict__ el3,
                                              const float* __restrict__ er3,
                                              const float* __restrict__ xsA,
                                              const float* __restrict__ xsB,
                                              unsigned short* __restrict__ aggX,
                                              int nd, int bpr)
{
    constexpr int NV = K / 64;                 // float4 chunks per lane
    __shared__ float exs[256][4];
    int bx = blockIdx.x;
    int r = (bx >= 2 * bpr) ? 2 : (bx >= bpr ? 1 : 0);
    int wid = ((bx - r * bpr) * 256 + (int)threadIdx.x) >> 6;
    int lane = threadIdx.x & 63;
    if (wid >= nd) return;                     // wave-uniform
    int q = lane & 15, g = lane >> 4;
    const float* el = el3 + (size_t)r * NSRC * 4;
    const float* xsrc = (r < 2) ? xsA : xsB;
    int c = cnt[(size_t)r * nd + wid]; if (c > CAP) c = CAP;   // wave-uniform
    const int* lst = bsrc + ((size_t)r * nd + wid) * CAP;
    float4 er4 = *reinterpret_cast<const float4*>(er3 + (size_t)r * NDST0 * 4 + (size_t)wid * 4);

    int s_own = 0;
    float4 ex_own = make_float4(0.f, 0.f, 0.f, 0.f);
    if (lane < c) {
        s_own = lst[lane];
        float4 e4 = *reinterpret_cast<const float4*>(el + (size_t)s_own * 4);
        e4.x += er4.x; e4.y += er4.y; e4.z += er4.z; e4.w += er4.w;
        e4.x = e4.x > 0.f ? e4.x : 0.2f * e4.x;
        e4.y = e4.y > 0.f ? e4.y : 0.2f * e4.y;
        e4.z = e4.z > 0.f ? e4.z : 0.2f * e4.z;
        e4.w = e4.w > 0.f ? e4.w : 0.2f * e4.w;
        ex_own.x = __expf(e4.x); ex_own.y = __expf(e4.y);
        ex_own.z = __expf(e4.z); ex_own.w = __expf(e4.w);   // shift-invariant softmax
    }
    // stash per-lane ex4 once; reads are wave-local (program order + lgkmcnt)
    *reinterpret_cast<float4*>(&exs[threadIdx.x][0]) = ex_own;
    const int wavebase = threadIdx.x & 192;    // wave's 64-slot stripe

    float4 acc[NV];
    #pragma unroll
    for (int v = 0; v < NV; ++v) acc[v] = make_float4(0.f, 0.f, 0.f, 0.f);
    float den = 0.f;

    for (int t = 0; t < c; ++t) {
        int s = __shfl(s_own, t, 64);          // full-exec shfl
        float ex = exs[wavebase + t][g];       // LDS broadcast (16 lanes same addr)
        const float4* xp = reinterpret_cast<const float4*>(xsrc + (size_t)s * K) + q * NV;
        #pragma unroll
        for (int v = 0; v < NV; ++v) fma4(acc[v], ex, xp[v]);
        den += ex;
    }
    float inv = den > 0.f ? 1.f / den : 0.f;
    unsigned short* op = aggX + (((size_t)r * nd + wid) * 4 + g) * K + q * 4 * NV;
    if (NV == 1) {
        uint2 w;
        w.x = pack2(acc[0].x * inv, acc[0].y * inv);
        w.y = pack2(acc[0].z * inv, acc[0].w * inv);
        *reinterpret_cast<uint2*>(op) = w;
    } else {
        uint4 w;
        w.x = pack2(acc[0].x * inv, acc[0].y * inv);
        w.y = pack2(acc[0].z * inv, acc[0].w * inv);
        w.z = pack2(acc[1].x * inv, acc[1].y * inv);
        w.w = pack2(acc[1].z * inv, acc[1].w * inv);
        *reinterpret_cast<uint4*>(op) = w;
    }
}

// GEMM for 3 relations in one launch. out (bf16) stride NDST0*HD per rel.
template<int K>
__global__ __launch_bounds__(256) void k_gemm3(const unsigned short* __restrict__ aggX,
                                               const unsigned short* __restrict__ Wt3,
                                               unsigned short* __restrict__ outb,
                                               int nd, int bpr)
{
    int bx = blockIdx.x;
    int r = (bx >= 2 * bpr) ? 2 : (bx >= bpr ? 1 : 0);
    const unsigned short* A  = aggX + (size_t)r * nd * 4 * K;
    const unsigned short* Wt = Wt3 + (size_t)r * 256 * K;
    unsigned short* ob = outb + (size_t)r * NDST0 * HD;
    const int lane = threadIdx.x & 63;
    const int wv = threadIdx.x >> 6;          // = head
    const int r0 = (bx - r * bpr) * 16;
    const int rr = lane & 15, kg = lane >> 4;
    f32x4 acc[4] = {{0.f,0.f,0.f,0.f},{0.f,0.f,0.f,0.f},{0.f,0.f,0.f,0.f},{0.f,0.f,0.f,0.f}};
    const unsigned short* ap = A + ((size_t)(r0 + rr) * 4 + wv) * K + kg * 8;
    #pragma unroll
    for (int kb = 0; kb < K; kb += 32) {
        bf16x8 a = *reinterpret_cast<const bf16x8*>(ap + kb);
        #pragma unroll
        for (int n = 0; n < 4; ++n) {
            const unsigned short* wp = Wt + (size_t)(wv * 64 + n * 16 + rr) * K + kb + kg * 8;
            bf16x8 b = *reinterpret_cast<const bf16x8*>(wp);
            acc[n] = __builtin_amdgcn_mfma_f32_16x16x32_bf16(a, b, acc[n], 0, 0, 0);
        }
    }
    #pragma unroll
    for (int n = 0; n < 4; ++n)
        #pragma unroll
        for (int i = 0; i < 4; ++i)
            ob[(size_t)(r0 + kg * 4 + i) * HD + wv * 64 + n * 16 + rr] = f2bf(acc[n][i]);
}

// Attention pool: 4 nodes per wave, 16 lanes per node (lane owns 4 dims). bf16 sources.
template<int S>
__global__ __launch_bounds__(256) void k_pool2(const unsigned short* __restrict__ srcA, const float* __restrict__ bA,
                                               const unsigned short* __restrict__ srcB, const float* __restrict__ bB,
                                               const float* __restrict__ base, int baseCols,
                                               float* __restrict__ dst, int pitch, int colOff, int n)
{
    int wid = (blockIdx.x * 256 + threadIdx.x) >> 6;
    int lane = threadIdx.x & 63;
    int node = wid * 4 + (lane >> 4);
    int q = lane & 15;
    if (node >= n) return;

    float4 f[S];
    #pragma unroll
    for (int s = 0; s < S; ++s) {
        const unsigned short* sp = (s < 4) ? (srcA + (size_t)node * HD + s * DD)
                                           : (srcB + (size_t)node * HD + (s - 4) * DD);
        const float* bp = (s < 4) ? (bA + s * DD) : (bB + (s - 4) * DD);
        float4 v = ld_bf4(sp + q * 4);
        float4 b = *reinterpret_cast<const float4*>(bp + q * 4);
        v.x += b.x; v.y += b.y; v.z += b.z; v.w += b.w;
        f[s] = v;
    }
    constexpr int NE = S * (S + 1) / 2;
    float gt[NE];
    {
        int idx = 0;
        #pragma unroll
        for (int s = 0; s < S; ++s)
            #pragma unroll
            for (int t = s; t < S; ++t)
                gt[idx++] = dot4(f[s], f[t]);
    }
    #pragma unroll
    for (int m = 1; m < 16; m <<= 1) {
        #pragma unroll
        for (int i = 0; i < NE; ++i) gt[i] += __shfl_xor(gt[i], m, 16);
    }
    auto Gv = [&](int s, int t) -> float {
        int a = s < t ? s : t, b2 = s < t ? t : s;
        return gt[a * S - a * (a - 1) / 2 + (b2 - a)];
    };
    float g[S];
    #pragma unroll
    for (int t = 0; t < S; ++t) g[t] = 0.f;
    #pragma unroll
    for (int s = 0; s < S; ++s) {
        float sc[S];
        float m = -1e30f;
        #pragma unroll
        for (int t = 0; t < S; ++t) { sc[t] = Gv(s, t) * 0.125f; m = sc[t] > m ? sc[t] : m; }
        float pe[S];
        float sum = 0.f;
        #pragma unroll
        for (int t = 0; t < S; ++t) { pe[t] = __expf(sc[t] - m); sum += pe[t]; }
        float inv = 1.f / sum;
        #pragma unroll
        for (int t = 0; t < S; ++t) g[t] += pe[t] * inv;
    }
    float4 o = make_float4(0.f, 0.f, 0.f, 0.f);
    #pragma unroll
    for (int t = 0; t < S; ++t) fma4(o, g[t], f[t]);
    const float is = 1.f / S;
    o.x *= is; o.y *= is; o.z *= is; o.w *= is;
    *reinterpret_cast<float4*>(dst + (size_t)node * pitch + colOff + q * 4) = o;
    for (int c = q * 4; c < baseCols; c += 64) {
        float4 v = *reinterpret_cast<const float4*>(base + (size_t)node * baseCols + c);
        *reinterpret_cast<float4*>(dst + (size_t)node * pitch + c) = v;
    }
}

extern "C" void kernel_launch(void* const* d_in, const int* in_sizes, int n_in,
                              void* d_out, int out_size, void* d_ws, size_t ws_size,
                              hipStream_t stream)
{
    const float* x_user = (const float*)d_in[0];
    const float* x_item = (const float*)d_in[1];
    // rel order within a layer: 0=ii 1=iu 2=ui
    const int* e_s[6] = { (const int*)d_in[2], (const int*)d_in[4], (const int*)d_in[6],
                          (const int*)d_in[8], (const int*)d_in[10], (const int*)d_in[12] };
    const int* e_d[6] = { (const int*)d_in[3], (const int*)d_in[5], (const int*)d_in[7],
                          (const int*)d_in[9], (const int*)d_in[11], (const int*)d_in[13] };
    const float* W0  = (const float*)d_in[14];
    const float* al0 = (const float*)d_in[15];
    const float* ar0 = (const float*)d_in[16];
    const float* b0  = (const float*)d_in[17];
    const float* W1  = (const float*)d_in[18];
    const float* al1 = (const float*)d_in[19];
    const float* ar1 = (const float*)d_in[20];
    const float* b1  = (const float*)d_in[21];
    float* out = (float*)d_out;
    (void)in_sizes; (void)n_in; (void)out_size; (void)ws_size;

    char* p = (char*)d_ws;
    auto take = [&](size_t bytes) { char* r = p; p += (bytes + 255) & ~(size_t)255; return r; };
    unsigned short* out3 = (unsigned short*)take((size_t)3 * NDST0 * HD * 2);  // 46.1 MB
    float* xu1  = (float*)take((size_t)NDST0 * 128 * 4);                       // 15.4 MB
    float* xi1  = (float*)take((size_t)NDST0 * 128 * 4);                       // 15.4 MB
    unsigned short* aggX = (unsigned short*)take((size_t)3 * NDST0 * 4 * DD * 2); // 46.1 MB
    float* el3  = (float*)take((size_t)3 * NSRC * 4 * 4);                      // 4.8 MB
    float* er3  = (float*)take((size_t)3 * NDST0 * 4 * 4);                     // 1.44 MB
    int*   cntA = (int*)take((size_t)3 * NDST0 * 4);
    int*   cntB = (int*)take((size_t)3 * NDST1 * 4);
    int*   bsrcA = (int*)take((size_t)3 * NDST0 * CAP * 4);                    // 23.0 MB
    int*   bsrcB = (int*)take((size_t)3 * NDST1 * CAP * 4);                    // 6.1 MB
    unsigned short* WtA = (unsigned short*)take((size_t)3 * 256 * 64 * 2);
    unsigned short* WtB = (unsigned short*)take((size_t)3 * 256 * 128 * 2);
    float* wlA = (float*)take((size_t)3 * 512 * 4);
    float* wrA = (float*)take((size_t)3 * 512 * 4);
    float* wlB = (float*)take((size_t)3 * 512 * 4);
    float* wrB = (float*)take((size_t)3 * 512 * 4);
    // total ~159 MB

    unsigned short* out_ii = out3;
    unsigned short* out_iu = out3 + (size_t)NDST0 * HD;
    unsigned short* out_ui = out3 + (size_t)2 * NDST0 * HD;

    // single memset covers cntA (padded) + cntB: contiguous takes
    {
        size_t cntSpan = (size_t)((char*)cntB - (char*)cntA) + (size_t)3 * NDST1 * 4;
        hipMemsetAsync(cntA, 0, cntSpan, stream);
    }
    const int bpr0 = (E0N + 255) / 256;
    const int bpr1 = (E1N + 255) / 256;
    k_setup<<<3 * bpr0 + 3 * bpr1 + 15, 256, 0, stream>>>(
        e_d[0], e_d[1], e_d[2], e_s[0], e_s[1], e_s[2],
        e_d[3], e_d[4], e_d[5], e_s[3], e_s[4], e_s[5],
        cntA, bsrcA, cntB, bsrcB,
        W0, al0, ar0, W1, al1, ar1,
        wlA, wrA, WtA, wlB, wrB, WtB, bpr0, bpr1);

    // ================= layer 1 (K=64) =================
    {
        const int bpr = (NSRC + 255) / 256;
        k_prep_x2<64><<<2 * bpr, 256, 0, stream>>>(x_item, x_user, NSRC, NDST0, bpr,
                                                   wlA, wrA, el3, er3);
        const int bprA = (NDST0 + 3) / 4;
        k_agg3<64><<<3 * bprA, 256, 0, stream>>>(cntA, bsrcA, el3, er3, x_item, x_user,
                                                 aggX, NDST0, bprA);
        const int bprG = NDST0 / 16;
        k_gemm3<64><<<3 * bprG, 256, 0, stream>>>(aggX, WtA, out3, NDST0, bprG);
    }
    k_pool2<4><<<NDST0 / 16, 256, 0, stream>>>(out_iu, b0 + 256, out_iu, b0 + 256,
                                               x_user, 64, xu1, 128, 64, NDST0);
    k_pool2<8><<<NDST0 / 16, 256, 0, stream>>>(out_ii, b0, out_ui, b0 + 512,
                                               x_item, 64, xi1, 128, 64, NDST0);

    // ================= layer 2 (K=128) =================
    {
        const int bpr = (NDST0 + 255) / 256;
        k_prep_x2<128><<<2 * bpr, 256, 0, stream>>>(xi1, xu1, NDST0, NDST1, bpr,
                                                    wlB, wrB, el3, er3);
        const int bprA = (NDST1 + 3) / 4;
        k_agg3<128><<<3 * bprA, 256, 0, stream>>>(cntB, bsrcB, el3, er3, xi1, xu1,
                                                  aggX, NDST1, bprA);
        const int bprG = NDST1 / 16;
        k_gemm3<128><<<3 * bprG, 256, 0, stream>>>(aggX, WtB, out3, NDST1, bprG);
    }
    k_pool2<4><<<NDST1 / 16, 256, 0, stream>>>(out_iu, b1 + 256, out_iu, b1 + 256,
                                               xu1, 128, out, 192, 128, NDST1);
    k_pool2<8><<<NDST1 / 16, 256, 0, stream>>>(out_ii, b1, out_ui, b1 + 512,
                                               xi1, 128, out + (size_t)NDST1 * 192, 192, 128, NDST1);
}